// Round 13
// baseline (186.342 us; speedup 1.0000x reference)
//
#include <hip/hip_runtime.h>
#include <math.h>

// Problem constants
#define KJ 24
#define NV 6890
#define PREG 200
#define M_TOT (NV*3)          // 20670
#define KDIM 391              // 23*17
#define KPAD 416              // 13 chunks of 32
#define TP_STRIDE 20672       // TP row stride (2 pad cols)
#define NMT64 323             // 64-wide m-tiles (kB)
#define NKB (NMT64*2)         // 646 kB blocks (m-tile x K-half) -> E_K partials

// Workspace layout (float offsets unless _U = ushort offsets). ~23 MB total.
#define EDP_OFF 0               // 675 E_D partials (kC 27 x 25)
#define EKP_OFF 5400            // 23*646 E_K partials (kB, fused)
#define WIP_OFF 101984          // 27 E_Wi partials
#define EWP_OFF 102016          // 27 E_W partials
#define EAP_OFF 102048          // 27 E_A partials
#define RED_OFF 102080          // 32 final partials
#define G_OFF   102112          // G' : 200 x 24 x 12 (ends float 159712)
#define TPH_OFF_U  319424       // T_p bf16, K-half 0 (200 x 20672 ushort)
#define TP2H_OFF_U 4453824      // T_p bf16, K-half 1
#define QBH_OFF_U 10903488      // qm hi bf16, 256 x 416
#define QBL_OFF_U 11009984      // qm lo bf16, 256 x 416

typedef __attribute__((ext_vector_type(8))) short short8;
typedef __attribute__((ext_vector_type(4))) float f32x4;
typedef __attribute__((ext_vector_type(4))) unsigned int u32x4;

__constant__ int c_PARENT[24] = {0,0,0,0,1,2,3,4,5,6,7,8,9,9,9,12,13,14,16,17,18,19,20,21};
__constant__ int c_DEPTH[24]  = {0,1,1,1,2,2,2,3,3,3,4,4,4,4,4,5,5,5,6,6,7,7,8,8};
__constant__ int c_LEN[24]    = {4,3,3,3,3,3,3,3,3,2,2,2,4,3,3,2,3,3,3,3,3,3,2,2};
__constant__ int c_NBR[24][4] = {
  {0,1,2,3},{0,1,4,0},{0,2,5,0},{0,3,6,0},{1,4,7,0},{2,5,8,0},{3,6,9,0},{4,7,10,0},
  {5,8,11,0},{6,9,0,0},{7,10,0,0},{8,11,0,0},{12,13,14,15},{12,13,16,0},{12,14,17,0},
  {12,15,0,0},{13,16,18,0},{14,17,19,0},{16,18,20,0},{17,19,21,0},{18,20,22,0},
  {19,21,23,0},{20,22,0,0},{21,23,0,0}};

__device__ __forceinline__ float waveReduce(float v) {
  #pragma unroll
  for (int off = 32; off > 0; off >>= 1) v += __shfl_down(v, off, 64);
  return v;
}
__device__ __forceinline__ unsigned short f2bf(float x) {
  union { float f; unsigned u; } v; v.f = x;
  unsigned r = v.u + 0x7FFFu + ((v.u >> 16) & 1u);
  return (unsigned short)(r >> 16);
}
__device__ __forceinline__ float bf2f(unsigned short h) {
  union { unsigned u; float f; } v; v.u = ((unsigned)h) << 16; return v.f;
}

// ---- kPre (77 blocks): b<50: pose math (4 p/block) -> G' + qm bf16 hi/lo
//      planes; b<77: E_Wi/E_W/E_A partials + qm pad-row zeroing. ----
__global__ __launch_bounds__(256) void kPre(const float* __restrict__ J,
                                            const float* __restrict__ theta,
                                            const float* __restrict__ beta2,
                                            const float* __restrict__ Wp,
                                            const float* __restrict__ Wi,
                                            const float* __restrict__ A,
                                            float* __restrict__ ws) {
  unsigned short* qbh = (unsigned short*)ws + QBH_OFF_U;
  unsigned short* qbl = (unsigned short*)ws + QBL_OFF_U;
  int b = blockIdx.x;
  if (b < 50) {
    __shared__ float Gl[4][24][12];
    __shared__ float Gg[4][24][12];
    __shared__ float q[4][24][4];
    int w = threadIdx.x >> 6, t = threadIdx.x & 63;
    int p = b*4 + w;
    if (t < 24) {
      float x = theta[p*72 + 3*t + 0];
      float y = theta[p*72 + 3*t + 1];
      float z = theta[p*72 + 3*t + 2];
      float n2 = x*x + y*y + z*z;
      float ang = fmaxf(sqrtf(n2), 1e-8f);
      float ia = 1.f/ang;
      float ax = x*ia, ay = y*ia, az = z*ia;
      float c = cosf(ang), s = sinf(ang), C = 1.f - c;
      float jx = J[p*72+3*t], jy = J[p*72+3*t+1], jz = J[p*72+3*t+2];
      float tx = jx, ty = jy, tz = jz;
      if (t > 0) {
        int par = c_PARENT[t];
        tx -= J[p*72+3*par]; ty -= J[p*72+3*par+1]; tz -= J[p*72+3*par+2];
      }
      Gl[w][t][0]=c+C*ax*ax;   Gl[w][t][1]=C*ax*ay-s*az; Gl[w][t][2]=C*ax*az+s*ay; Gl[w][t][3]=tx;
      Gl[w][t][4]=C*ax*ay+s*az;Gl[w][t][5]=c+C*ay*ay;    Gl[w][t][6]=C*ay*az-s*ax; Gl[w][t][7]=ty;
      Gl[w][t][8]=C*ax*az-s*ay;Gl[w][t][9]=C*ay*az+s*ax; Gl[w][t][10]=c+C*az*az;   Gl[w][t][11]=tz;
      float ang2 = sqrtf(fmaxf(n2, 1e-16f));
      float inv2 = 1.f/ang2;
      float s2 = sinf(0.5f*ang2);
      q[w][t][0] = x*inv2*s2; q[w][t][1] = y*inv2*s2; q[w][t][2] = z*inv2*s2;
      q[w][t][3] = cosf(0.5f*ang2) - 1.f;
    }
    __syncthreads();
    for (int lev = 0; lev <= 8; lev++) {
      if (t < 24 && c_DEPTH[t] == lev) {
        if (lev == 0) {
          for (int i2 = 0; i2 < 12; i2++) Gg[w][0][i2] = Gl[w][0][i2];
        } else {
          int par = c_PARENT[t];
          for (int r = 0; r < 3; r++) {
            float g0 = Gg[w][par][r*4+0], g1 = Gg[w][par][r*4+1];
            float g2 = Gg[w][par][r*4+2], g3 = Gg[w][par][r*4+3];
            for (int c2 = 0; c2 < 4; c2++) {
              float v = g0*Gl[w][t][0+c2] + g1*Gl[w][t][4+c2] + g2*Gl[w][t][8+c2];
              if (c2 == 3) v += g3;
              Gg[w][t][r*4+c2] = v;
            }
          }
        }
      }
      __syncthreads();
    }
    if (t < 24) {
      float jx = J[p*72+3*t], jy = J[p*72+3*t+1], jz = J[p*72+3*t+2];
      float* gp = ws + G_OFF + p*288 + t*12;
      #pragma unroll
      for (int r = 0; r < 3; r++) {
        float off = Gg[w][t][r*4+0]*jx + Gg[w][t][r*4+1]*jy + Gg[w][t][r*4+2]*jz;
        Gg[w][t][r*4+3] -= off;
      }
      #pragma unroll
      for (int i2 = 0; i2 < 12; i2++) gp[i2] = Gg[w][t][i2];
    }
    __syncthreads();
    float b2 = beta2[0];
    for (int e = t; e < KDIM; e += 64) {
      int j = e / 17, l = e - 17*j;
      int k = j + 1;
      float val = 0.f;
      if (l < 4*c_LEN[j] + 1) {
        if (l < 16) {
          int sidx = l >> 2, cc = l & 3;
          if (sidx < c_LEN[k]) val = q[w][c_NBR[k][sidx]][cc];
        }
        if (l == 4*c_LEN[k]) val += b2;
      }
      unsigned short hi = f2bf(val);
      unsigned short lo = f2bf(val - bf2f(hi));
      qbh[p*KPAD + e] = hi;
      qbl[p*KPAD + e] = lo;
    }
    for (int e = KDIM + t; e < KPAD; e += 64) {
      qbh[p*KPAD + e] = 0; qbl[p*KPAD + e] = 0;
    }
  } else {
    int d = b - 50;                        // 0..26
    int t = threadIdx.x;
    int n = d*256 + t;
    float ewi = 0.f, ew = 0.f, ea = 0.f;
    if (n < NV) {
      float wv[24]; float sum = 0.f;
      const float4* wp4 = (const float4*)(Wp + n*24);
      #pragma unroll
      for (int i = 0; i < 6; i++) {
        float4 v4 = wp4[i];
        wv[4*i+0] = fmaxf(v4.x, 0.f); wv[4*i+1] = fmaxf(v4.y, 0.f);
        wv[4*i+2] = fmaxf(v4.z, 0.f); wv[4*i+3] = fmaxf(v4.w, 0.f);
        sum += wv[4*i+0]+wv[4*i+1]+wv[4*i+2]+wv[4*i+3];
      }
      float inv = 1.f/(sum + 1e-8f);
      #pragma unroll
      for (int k = 0; k < 24; k++) {
        float wc = wv[k]*inv;
        ew += fabsf(wc);
        float dd = wc - Wi[n*24+k];
        ewi += dd*dd;
      }
    }
    for (int i = d*256 + t; i < 23*NV; i += 27*256) ea += fabsf(A[i]);
    for (int i = d*256 + t; i < 56*KPAD; i += 27*256) {
      qbh[200*KPAD + i] = 0; qbl[200*KPAD + i] = 0;
    }
    __shared__ float red[3][4];
    int lane = t & 63, wv2 = t >> 6;
    ewi = waveReduce(ewi); ew = waveReduce(ew); ea = waveReduce(ea);
    if (lane == 0) { red[0][wv2] = ewi; red[1][wv2] = ew; red[2][wv2] = ea; }
    __syncthreads();
    if (t == 0) {
      ws[WIP_OFF + d] = red[0][0]+red[0][1]+red[0][2]+red[0][3];
      ws[EWP_OFF + d] = red[1][0]+red[1][1]+red[1][2]+red[1][3];
      ws[EAP_OFF + d] = red[2][0]+red[2][1]+red[2][2]+red[2][3];
    }
  }
}

// ---- kB: FUSED transpose + split-bf16 MFMA GEMM, ONE barrier per K-step.
//      R12 (kB=70.8us) counters: all pipes <15%, 5150 cyc/step vs ~1200
//      modeled — causes: 2 barrier drains/step, 32 LDS atomics/step,
//      late-issued loads paying full latency in the vmcnt(0) drain, kv
//      consumed same-iter. This is R9's schedule (correctness PASSED in R9)
//      with the codegen poison removed: NO runtime-indexed register arrays
//      (R9's kv[2][8][ks&1] in runtime-param lambdas -> scratch). kvA/kvB
//      are named arrays selected by literal-folded branches via MACROS.
//      Iter ks: loadK(ks+3)[top] | SB-read+MFMA(ks) | qm-pref(ks+2) |
//               stageK(ks+2) | xpose(ks+1) | ONE barrier.
//      E_K via single-writer ek2[] (no atomics), epilogue reduce. ----
template<int KS0, int NKS, int JMIN>
__device__ __forceinline__ void kb_body(const float* __restrict__ A,
                                        const float* __restrict__ K,
                                        const unsigned short* __restrict__ qbh,
                                        const unsigned short* __restrict__ qbl,
                                        float (*__restrict__ Sk)[32*66],
                                        short (*__restrict__ SBh)[64*32],
                                        short (*__restrict__ SBl)[64*32],
                                        float (*__restrict__ SA)[24],
                                        float* __restrict__ ek2,
                                        float* __restrict__ ws,
                                        unsigned short* __restrict__ TPd,
                                        int m0, int flat) {
  const int tid = threadIdx.x;
  const int w = tid >> 6, lane = tid & 63;
  const int r = lane & 15, qd = lane >> 4;
  const int krow = tid >> 3, mseg = (tid & 7) * 8;
  const int mm = m0 + mseg;
  const int nb0 = m0 / 3;
  const int mrow2 = tid >> 2, kq2 = tid & 3;
  const int swr = ((mrow2 >> 4)*64 + kq2*16 + (mrow2 & 15)) * 8;

  // relu(A) window
  for (int i = tid; i < 14*24; i += 256) {
    int jj = i / 24, nn = i - jj*24;
    int j2 = JMIN + jj, n2 = nb0 + nn;
    ((float*)SA)[i] = (j2 < 23 && n2 < NV) ? fmaxf(A[j2*NV + n2], 0.f) : 0.f;
  }

  f32x4 acc[4][4];
  #pragma unroll
  for (int h = 0; h < 4; h++)
    #pragma unroll
    for (int f = 0; f < 4; f++) acc[h][f] = (f32x4){0.f,0.f,0.f,0.f};

  int aofs[4];
  #pragma unroll
  for (int h = 0; h < 4; h++) aofs[h] = (w*64 + h*16 + r)*KPAD + KS0*32 + qd*8;

  short8 ah[2][4], al[2][4];
  float kvA[8], kvB[8];

  // ---- macros: KSV is always a LITERAL at expansion; KV is a NAMED array ----
#define LOADK(KSV, KV) do {                                                    \
    int kg_ = (KS0 + (KSV))*32 + krow;                                         \
    for (int i_ = 0; i_ < 8; i_++) KV[i_] = 0.f;                               \
    if (kg_ < KDIM) {                                                          \
      const float* kr_ = K + (size_t)kg_*M_TOT + mm;                           \
      if (mm + 7 < M_TOT) {                                                    \
        float4 a4_ = *(const float4*)kr_; float4 b4_ = *(const float4*)(kr_+4);\
        KV[0]=a4_.x; KV[1]=a4_.y; KV[2]=a4_.z; KV[3]=a4_.w;                    \
        KV[4]=b4_.x; KV[5]=b4_.y; KV[6]=b4_.z; KV[7]=b4_.w;                    \
      } else {                                                                 \
        for (int i_ = 0; i_ < 8; i_++) if (mm+i_ < M_TOT) KV[i_] = kr_[i_];    \
      }                                                                        \
    } } while (0)

#define STAGEK(KSV, KV) do {                                                   \
    int kg_ = (KS0 + (KSV))*32 + krow;                                         \
    float wv_[8]; float sq_ = 0.f;                                             \
    for (int i_ = 0; i_ < 8; i_++) wv_[i_] = 0.f;                              \
    if (kg_ < KDIM) {                                                          \
      int jj_ = kg_/17 - JMIN;                                                 \
      int nb_ = mm / 3;                                                        \
      float av_[4];                                                            \
      for (int i_ = 0; i_ < 4; i_++) av_[i_] = SA[jj_][nb_ - nb0 + i_];        \
      for (int i_ = 0; i_ < 8; i_++) {                                         \
        float a_ = (mm+i_ < M_TOT) ? av_[(mm+i_)/3 - nb_] : 0.f;               \
        wv_[i_] = KV[i_]*a_;                                                   \
        sq_ = fmaf(KV[i_], KV[i_], sq_);                                       \
      }                                                                        \
    }                                                                          \
    for (int c_ = 0; c_ < 4; c_++)                                             \
      *(float2*)&Sk[(KSV)&1][krow*66 + mseg + 2*c_] =                          \
        make_float2(wv_[2*c_], wv_[2*c_+1]);                                   \
    sq_ += __shfl_xor(sq_, 1, 64);                                             \
    sq_ += __shfl_xor(sq_, 2, 64);                                             \
    sq_ += __shfl_xor(sq_, 4, 64);                                             \
    if ((tid & 7) == 0) ek2[(KSV)*32 + krow] = sq_;                            \
  } while (0)

#define XPOSE(KSV) do {                                                        \
    float vv_[8];                                                              \
    for (int j_ = 0; j_ < 8; j_++)                                             \
      vv_[j_] = Sk[(KSV)&1][(kq2*8 + j_)*66 + mrow2];                          \
    unsigned dh_[4], dl_[4];                                                   \
    for (int c_ = 0; c_ < 4; c_++) {                                           \
      unsigned short h0_ = f2bf(vv_[2*c_]),   h1_ = f2bf(vv_[2*c_+1]);         \
      unsigned short l0_ = f2bf(vv_[2*c_]   - bf2f(h0_));                      \
      unsigned short l1_ = f2bf(vv_[2*c_+1] - bf2f(h1_));                      \
      dh_[c_] = (unsigned)h0_ | ((unsigned)h1_ << 16);                         \
      dl_[c_] = (unsigned)l0_ | ((unsigned)l1_ << 16);                         \
    }                                                                          \
    *(u32x4*)&SBh[(KSV)&1][swr] = (u32x4){dh_[0], dh_[1], dh_[2], dh_[3]};     \
    *(u32x4*)&SBl[(KSV)&1][swr] = (u32x4){dl_[0], dl_[1], dl_[2], dl_[3]};     \
  } while (0)

  // ---- prologue: fill 2-deep pipeline (parity: loadK(j) -> kvA if j even) ----
  LOADK(0, kvA);
  #pragma unroll
  for (int h = 0; h < 4; h++) {
    ah[0][h] = *(const short8*)(qbh + aofs[h]);
    al[0][h] = *(const short8*)(qbl + aofs[h]);
  }
  STAGEK(0, kvA);                          // Sk[0]
  LOADK(1, kvB);
  __syncthreads();                         // Sk[0] visible
  XPOSE(0);                                // SB[0]
  STAGEK(1, kvB);                          // Sk[1] (prologue-only short cover)
  LOADK(2, kvA);
  #pragma unroll
  for (int h = 0; h < 4; h++) {
    ah[1][h] = *(const short8*)(qbh + aofs[h] + 32);
    al[1][h] = *(const short8*)(qbl + aofs[h] + 32);
  }
  __syncthreads();                         // SB[0], Sk[1] visible

  #pragma unroll
  for (int ks = 0; ks < NKS; ks++) {
    const int cur = ks & 1;
    // 1. issue next K load FIRST (max absorption before this iter's drain)
    //    set[(ks+3)&1]: last read by STAGEK(ks+1) at iter ks-1 (program order OK)
    if (ks + 3 < NKS) {
      if (cur == 1) LOADK(ks + 3, kvA); else LOADK(ks + 3, kvB);
    }
    // 2. B frags from SB[cur] (written by xpose(ks) one barrier ago)
    short8 bfh[4], bfl[4];
    #pragma unroll
    for (int f = 0; f < 4; f++) {
      bfh[f] = *(const short8*)&SBh[cur][(f*64 + lane)*8];
      bfl[f] = *(const short8*)&SBl[cur][(f*64 + lane)*8];
    }
    // 3. MFMA cluster
    #pragma unroll
    for (int f = 0; f < 4; f++)
      #pragma unroll
      for (int h = 0; h < 4; h++) {
        acc[h][f] = __builtin_amdgcn_mfma_f32_16x16x32_bf16(ah[cur][h], bfh[f], acc[h][f], 0, 0, 0);
        acc[h][f] = __builtin_amdgcn_mfma_f32_16x16x32_bf16(ah[cur][h], bfl[f], acc[h][f], 0, 0, 0);
        acc[h][f] = __builtin_amdgcn_mfma_f32_16x16x32_bf16(al[cur][h], bfh[f], acc[h][f], 0, 0, 0);
      }
    // 4. qm frag prefetch for ks+2 into slot cur (just freed by this MFMA)
    if (ks + 2 < NKS) {
      const int o = (ks + 2) * 32;
      #pragma unroll
      for (int h = 0; h < 4; h++) {
        ah[cur][h] = *(const short8*)(qbh + aofs[h] + o);
        al[cur][h] = *(const short8*)(qbl + aofs[h] + o);
      }
    }
    // 5. stage K(ks+2): kv loaded at iter ks-1 -> FULL-iteration cover.
    //    Writes Sk[ks&1], last read by xpose(ks) at iter ks-1 (barrier between).
    if (ks + 2 < NKS) {
      if (cur == 0) STAGEK(ks + 2, kvA); else STAGEK(ks + 2, kvB);
    }
    // 6. transpose Sk[(ks+1)&1] (staged iter ks-1) -> SB[(ks+1)&1]
    //    (SB slot last read at iter ks-1, barrier between).
    if (ks + 1 < NKS) XPOSE(ks + 1);
    // 7. the ONE barrier
    __syncthreads();
  }
#undef LOADK
#undef STAGEK
#undef XPOSE

  // ---- E_K epilogue reduce (single-writer partials; no atomics) ----
  if (tid < 23) {
    float s = 0.f;
    for (int i2 = 0; i2 < NKS*32; i2++) {
      int kg = KS0*32 + i2;
      if (kg < KDIM && kg/17 == tid) s += ek2[i2];
    }
    ws[EKP_OFF + tid*NKB + flat] = s;
  }
  // ---- C write (bf16) ----
  #pragma unroll
  for (int h = 0; h < 4; h++)
    #pragma unroll
    for (int f = 0; f < 4; f++)
      #pragma unroll
      for (int g = 0; g < 4; g++) {
        int p = w*64 + h*16 + qd*4 + g;
        if (p < PREG)
          TPd[(size_t)p*TP_STRIDE + m0 + f*16 + r] = f2bf(acc[h][f][g]);
      }
}

__global__ __launch_bounds__(256) void kB(const float* __restrict__ A,
                                          const float* __restrict__ K,
                                          float* __restrict__ ws) {
  __shared__ float Sk[2][32*66];           // 16.9 KB (dbuf)
  __shared__ short SBh[2][64*32];          // 8 KB
  __shared__ short SBl[2][64*32];          // 8 KB
  __shared__ float SA[14][24];             // relu(A) window
  __shared__ float ek2[7*32];              // per-(ks,krow) E_K partials
  const unsigned short* qbh = (const unsigned short*)ws + QBH_OFF_U;
  const unsigned short* qbl = (const unsigned short*)ws + QBL_OFF_U;
  unsigned short* tph  = (unsigned short*)ws + TPH_OFF_U;
  unsigned short* tp2h = (unsigned short*)ws + TP2H_OFF_U;
  const int m0 = blockIdx.x * 64;
  const int flat = blockIdx.x + blockIdx.y * NMT64;
  if (blockIdx.y == 0)
    kb_body<0, 7, 0>(A, K, qbh, qbl, Sk, SBh, SBl, SA, ek2, ws, tph,  m0, flat);
  else
    kb_body<7, 6, 13>(A, K, qbh, qbl, Sk, SBh, SBl, SA, ek2, ws, tp2h, m0, flat);
}

// ---- kC: skinning + verts + E_D. 1 vert/thread, 8 poses/block
//      (grid 27 x 25): Wp read ONCE per block. G via wave-uniform pointer
//      -> s_loads. T_p read as bf16. ----
__global__ __launch_bounds__(256) void kC(const float* __restrict__ V,
                                          const float* __restrict__ T,
                                          const float* __restrict__ Wp,
                                          const float* __restrict__ ws,
                                          float* __restrict__ out) {
  int p0 = blockIdx.y * 8;
  int n = blockIdx.x*256 + threadIdx.x;
  const unsigned short* tph  = (const unsigned short*)ws + TPH_OFF_U;
  const unsigned short* tp2h = (const unsigned short*)ws + TP2H_OFF_U;
  __shared__ float tmp[4];
  float ed = 0.f;
  if (n < NV) {
    float wv[24]; float sum = 0.f;
    const float4* wp4 = (const float4*)(Wp + n*24);
    #pragma unroll
    for (int i = 0; i < 6; i++) {
      float4 v4 = wp4[i];
      wv[4*i+0] = fmaxf(v4.x, 0.f); wv[4*i+1] = fmaxf(v4.y, 0.f);
      wv[4*i+2] = fmaxf(v4.z, 0.f); wv[4*i+3] = fmaxf(v4.w, 0.f);
      sum += wv[4*i+0]+wv[4*i+1]+wv[4*i+2]+wv[4*i+3];
    }
    float inv = 1.f/(sum + 1e-8f);
    for (int pp = 0; pp < 8; pp++) {
      int p = p0 + pp;
      const float* __restrict__ gp = ws + G_OFF + (size_t)p*288;  // uniform -> s_load
      float M[12];
      #pragma unroll
      for (int i = 0; i < 12; i++) M[i] = 0.f;
      #pragma unroll
      for (int k = 0; k < 24; k++) {
        float wc = wv[k];
        #pragma unroll
        for (int i = 0; i < 12; i++)
          M[i] = fmaf(wc, gp[k*12 + i], M[i]);   // sgpr src0
      }
      #pragma unroll
      for (int i = 0; i < 12; i++) M[i] *= inv;
      size_t tb = (size_t)p*M_TOT + 3*n;
      size_t pb = (size_t)p*TP_STRIDE + 3*n;
      float t0 = bf2f(tph[pb + 0]) + bf2f(tp2h[pb + 0]) + T[tb + 0];
      float t1 = bf2f(tph[pb + 1]) + bf2f(tp2h[pb + 1]) + T[tb + 1];
      float t2 = bf2f(tph[pb + 2]) + bf2f(tp2h[pb + 2]) + T[tb + 2];
      float v0 = M[0]*t0 + M[1]*t1 + M[2]*t2  + M[3];
      float v1 = M[4]*t0 + M[5]*t1 + M[6]*t2  + M[7];
      float v2 = M[8]*t0 + M[9]*t1 + M[10]*t2 + M[11];
      out[1+tb+0] = v0; out[1+tb+1] = v1; out[1+tb+2] = v2;
      float d0 = V[tb+0]-v0, d1 = V[tb+1]-v1, d2 = V[tb+2]-v2;
      ed += d0*d0 + d1*d1 + d2*d2;
    }
  }
  ed = waveReduce(ed);
  int lane = threadIdx.x & 63, w = threadIdx.x >> 6;
  if (lane == 0) tmp[w] = ed;
  __syncthreads();
  if (threadIdx.x == 0)
    ((float*)ws)[EDP_OFF + blockIdx.y*27 + blockIdx.x] = tmp[0]+tmp[1]+tmp[2]+tmp[3];
}

// ---- kF1: parallel partial reductions (25 blocks) ----
__global__ __launch_bounds__(256) void kF1(float* __restrict__ ws) {
  __shared__ float sb[4];
  int b = blockIdx.x, t = threadIdx.x, lane = t & 63, w = t >> 6;
  if (b < 23) {
    float s = 0.f;
    for (int i = t; i < NKB; i += 256) s += ws[EKP_OFF + b*NKB + i];
    s = waveReduce(s);
    if (lane == 0) sb[w] = s;
    __syncthreads();
    if (t == 0) ws[RED_OFF + b] = sb[0]+sb[1]+sb[2]+sb[3];
  } else if (b == 23) {
    float s = 0.f;
    for (int i = t; i < 675; i += 256) s += ws[EDP_OFF + i];
    s = waveReduce(s);
    if (lane == 0) sb[w] = s;
    __syncthreads();
    if (t == 0) ws[RED_OFF + 23] = sb[0]+sb[1]+sb[2]+sb[3];
  } else {
    if (w == 0) {
      float s = (lane < 27) ? ws[WIP_OFF + lane] : 0.f;
      s = waveReduce(s);
      if (lane == 0) ws[RED_OFF + 24] = s;
    } else if (w == 1) {
      float s = (lane < 27) ? ws[EWP_OFF + lane] : 0.f;
      s = waveReduce(s);
      if (lane == 0) ws[RED_OFF + 25] = s;
    } else if (w == 2) {
      float s = (lane < 27) ? ws[EAP_OFF + lane] : 0.f;
      s = waveReduce(s);
      if (lane == 0) ws[RED_OFF + 26] = s;
    }
  }
}

// ---- kF2: final combine ----
__global__ void kF2(const int* __restrict__ epoch, const float* __restrict__ ws,
                    float* __restrict__ out) {
  int t = threadIdx.x;
  float s = (t < 23) ? sqrtf(ws[RED_OFF + t]) : 0.f;
  s = waveReduce(s);
  if (t == 0) {
    float e    = (float)epoch[0];
    float g_wi = 0.1f   * expf(-0.1f  * e);
    float g_w  = 0.002f * expf(-0.008f* e);
    float g_a  = 0.001f * expf(-0.008f* e);
    float g_k  = 0.1f   * expf(-0.008f* e);
    out[0] = ws[RED_OFF+23] + g_wi*ws[RED_OFF+24] + g_w*ws[RED_OFF+25]
           + g_a*ws[RED_OFF+26] + g_k*s;
  }
}

extern "C" void kernel_launch(void* const* d_in, const int* in_sizes, int n_in,
                              void* d_out, int out_size, void* d_ws, size_t ws_size,
                              hipStream_t stream) {
  const float* V     = (const float*)d_in[0];
  const float* T     = (const float*)d_in[1];
  const float* J     = (const float*)d_in[2];
  const float* theta = (const float*)d_in[3];
  const float* Wp    = (const float*)d_in[4];
  const float* Wi    = (const float*)d_in[5];
  const float* A     = (const float*)d_in[6];
  const float* K     = (const float*)d_in[7];
  const float* b2    = (const float*)d_in[8];
  const int*   epoch = (const int*)d_in[9];
  float* out = (float*)d_out;
  float* ws  = (float*)d_ws;
  // needs ~23 MB workspace

  hipLaunchKernelGGL(kPre, dim3(77),        dim3(256), 0, stream,
                     J, theta, b2, Wp, Wi, A, ws);
  hipLaunchKernelGGL(kB,   dim3(NMT64, 2),  dim3(256), 0, stream, A, K, ws);
  hipLaunchKernelGGL(kC,   dim3(27, 25),    dim3(256), 0, stream, V, T, Wp, ws, out);
  hipLaunchKernelGGL(kF1,  dim3(25),        dim3(256), 0, stream, ws);
  hipLaunchKernelGGL(kF2,  dim3(1),         dim3(64),  0, stream, epoch, ws, out);
}